// Round 1
// baseline (376.925 us; speedup 1.0000x reference)
//
#include <hip/hip_runtime.h>
#include <cstdint>
#include <cstddef>

typedef unsigned long long ull;

#define N_ROWS 8192
#define D_K    64
#define SPAN   8187u   // n - k = 8192 - 5
#define MULT   1600u   // (2^32) % 8187
#define TAU_INV 10.0f
#define TOTAL_SAMP 163840u  // 8192*20

// ---------------- threefry2x32 (JAX-compatible) ----------------
__device__ __forceinline__ void tf_round(unsigned &x0, unsigned &x1, int r) {
    x0 += x1;
    x1 = (x1 << r) | (x1 >> (32 - r));
    x1 ^= x0;
}

__device__ __forceinline__ void threefry2x32(unsigned k0, unsigned k1,
                                             unsigned c0, unsigned c1,
                                             unsigned &o0, unsigned &o1) {
    unsigned ks2 = k0 ^ k1 ^ 0x1BD11BDAu;
    unsigned x0 = c0 + k0, x1 = c1 + k1;
    tf_round(x0, x1, 13); tf_round(x0, x1, 15); tf_round(x0, x1, 26); tf_round(x0, x1, 6);
    x0 += k1;  x1 += ks2 + 1u;
    tf_round(x0, x1, 17); tf_round(x0, x1, 29); tf_round(x0, x1, 16); tf_round(x0, x1, 24);
    x0 += ks2; x1 += k0 + 2u;
    tf_round(x0, x1, 13); tf_round(x0, x1, 15); tf_round(x0, x1, 26); tf_round(x0, x1, 6);
    x0 += k0;  x1 += k1 + 3u;
    tf_round(x0, x1, 17); tf_round(x0, x1, 29); tf_round(x0, x1, 16); tf_round(x0, x1, 24);
    x0 += k1;  x1 += ks2 + 4u;
    tf_round(x0, x1, 13); tf_round(x0, x1, 15); tf_round(x0, x1, 26); tf_round(x0, x1, 6);
    x0 += ks2; x1 += k0 + 5u;
    o0 = x0; o1 = x1;
}

// ---------------- Kernel 1: norms + inverse (1 - ns) ----------------
__global__ void norms_kernel(const float* __restrict__ X,
                             float* __restrict__ ns_g,
                             float* __restrict__ iv_g) {
    int r = blockIdx.x * blockDim.x + threadIdx.x;
    if (r >= N_ROWS) return;
    const float4* xf = (const float4*)(X + (size_t)r * D_K);
    float s = 0.f;
#pragma unroll
    for (int i = 0; i < 16; ++i) {
        float4 v = xf[i];
        s = fmaf(v.x, v.x, s);
        s = fmaf(v.y, v.y, s);
        s = fmaf(v.z, v.z, s);
        s = fmaf(v.w, v.w, s);
    }
    ns_g[r] = s;
    // (1 - EPS) rounds to 1.0f in fp32; points are strictly inside the ball
    iv_g[r] = 1.0f / (1.0f - fminf(s, 1.0f));
}

// ---------------- Kernel 2: tiled gram + fused per-row top-5 ----------------
// grid = 512: (row_tile = bx>>2, j_chunk = bx&3); 64-row tile, chunk = 2048 cols
__launch_bounds__(256, 2)
__global__ void topk_gram_kernel(const float* __restrict__ X,
                                 const float* __restrict__ ns_g,
                                 const float* __restrict__ iv_g,
                                 ull* __restrict__ part) {
    __shared__ float Atile[64][68];
    __shared__ float nsA[64], ivA[64];
    // union region: B tile + its norms during the main loop; dump buffer after
    __shared__ __align__(16) char ubuf[64 * 16 * 5 * 8]; // 40960 B >= 17920 B
    float (*Btile)[68] = (float (*)[68])ubuf;
    float* nsB = (float*)(ubuf + 64 * 68 * 4);
    float* ivB = nsB + 64;
    ull* dmp = (ull*)ubuf;   // [64 rows][16 thr][5]

    const int t  = threadIdx.x;
    const int tx = t & 15;
    const int ty = t >> 4;
    const int bx = blockIdx.x;
    const int r0 = (bx >> 2) * 64;
    const int ch = bx & 3;
    const int j0base = ch * 2048;

    const float4* Xf4 = (const float4*)X;

    // stage A tile (rows r0..r0+63), transposed: Atile[k][row]
#pragma unroll
    for (int i = 0; i < 4; ++i) {
        int f4   = t + i * 256;        // 0..1023
        int arow = f4 >> 4;
        int kv   = f4 & 15;
        float4 v = Xf4[(size_t)(r0 + arow) * 16 + kv];
        Atile[kv * 4 + 0][arow] = v.x;
        Atile[kv * 4 + 1][arow] = v.y;
        Atile[kv * 4 + 2][arow] = v.z;
        Atile[kv * 4 + 3][arow] = v.w;
    }
    if (t < 64) { nsA[t] = ns_g[r0 + t]; ivA[t] = iv_g[r0 + t]; }
    __syncthreads();

    float rns[4], riv[4];
#pragma unroll
    for (int i = 0; i < 4; ++i) { rns[i] = nsA[ty * 4 + i]; riv[i] = ivA[ty * 4 + i]; }

    // per-thread top-5 keys (packed (z_bits<<32)|col), for 4 owned rows
    ull t5[4][5];
#pragma unroll
    for (int i = 0; i < 4; ++i)
#pragma unroll
        for (int s = 0; s < 5; ++s) t5[i][s] = ~0ull;

    for (int tile = 0; tile < 32; ++tile) {
        const int j0 = j0base + tile * 64;
        // stage B tile transposed
#pragma unroll
        for (int i = 0; i < 4; ++i) {
            int f4   = t + i * 256;
            int bcol = f4 >> 4;
            int kv   = f4 & 15;
            float4 v = Xf4[(size_t)(j0 + bcol) * 16 + kv];
            Btile[kv * 4 + 0][bcol] = v.x;
            Btile[kv * 4 + 1][bcol] = v.y;
            Btile[kv * 4 + 2][bcol] = v.z;
            Btile[kv * 4 + 3][bcol] = v.w;
        }
        if (t < 64) { nsB[t] = ns_g[j0 + t]; ivB[t] = iv_g[j0 + t]; }
        __syncthreads();

        float cns[4], civ[4];
#pragma unroll
        for (int j = 0; j < 4; ++j) { cns[j] = nsB[tx * 4 + j]; civ[j] = ivB[tx * 4 + j]; }

        float acc[4][4];
#pragma unroll
        for (int i = 0; i < 4; ++i)
#pragma unroll
            for (int j = 0; j < 4; ++j) acc[i][j] = 0.f;

#pragma unroll 8
        for (int k = 0; k < 64; ++k) {
            float4 av = *(const float4*)&Atile[k][ty * 4];
            float4 bv = *(const float4*)&Btile[k][tx * 4];
            acc[0][0] = fmaf(av.x, bv.x, acc[0][0]);
            acc[0][1] = fmaf(av.x, bv.y, acc[0][1]);
            acc[0][2] = fmaf(av.x, bv.z, acc[0][2]);
            acc[0][3] = fmaf(av.x, bv.w, acc[0][3]);
            acc[1][0] = fmaf(av.y, bv.x, acc[1][0]);
            acc[1][1] = fmaf(av.y, bv.y, acc[1][1]);
            acc[1][2] = fmaf(av.y, bv.z, acc[1][2]);
            acc[1][3] = fmaf(av.y, bv.w, acc[1][3]);
            acc[2][0] = fmaf(av.z, bv.x, acc[2][0]);
            acc[2][1] = fmaf(av.z, bv.y, acc[2][1]);
            acc[2][2] = fmaf(av.z, bv.z, acc[2][2]);
            acc[2][3] = fmaf(av.z, bv.w, acc[2][3]);
            acc[3][0] = fmaf(av.w, bv.x, acc[3][0]);
            acc[3][1] = fmaf(av.w, bv.y, acc[3][1]);
            acc[3][2] = fmaf(av.w, bv.z, acc[3][2]);
            acc[3][3] = fmaf(av.w, bv.w, acc[3][3]);
        }

        // candidates: z = 1 + 2*d2 * inv_i * inv_j (monotone proxy for dist)
#pragma unroll
        for (int ri = 0; ri < 4; ++ri) {
            const int gr = r0 + ty * 4 + ri;
#pragma unroll
            for (int cj = 0; cj < 4; ++cj) {
                const int gc = j0 + tx * 4 + cj;
                float d2 = fmaxf(rns[ri] + cns[cj] - 2.0f * acc[ri][cj], 0.0f);
                float z  = fmaf(d2 * (riv[ri] * civ[cj]), 2.0f, 1.0f);
                z = fmaxf(z, 1.0f);
                ull kk = ((ull)__float_as_uint(z) << 32) | (unsigned)gc;
                if (gc == gr) kk = ~0ull;  // diagonal -> inf dist
                if (kk < t5[ri][4]) {
                    bool l3 = kk < t5[ri][3];
                    bool l2 = kk < t5[ri][2];
                    bool l1 = kk < t5[ri][1];
                    bool l0 = kk < t5[ri][0];
                    t5[ri][4] = l3 ? t5[ri][3] : kk;
                    t5[ri][3] = l3 ? (l2 ? t5[ri][2] : kk) : t5[ri][3];
                    t5[ri][2] = l2 ? (l1 ? t5[ri][1] : kk) : t5[ri][2];
                    t5[ri][1] = l1 ? (l0 ? t5[ri][0] : kk) : t5[ri][1];
                    t5[ri][0] = l0 ? kk : t5[ri][0];
                }
            }
        }
        __syncthreads();
    }

    // dump per-thread top5 and merge to per-row chunk top5
#pragma unroll
    for (int ri = 0; ri < 4; ++ri)
#pragma unroll
        for (int s = 0; s < 5; ++s)
            dmp[(ty * 4 + ri) * 80 + tx * 5 + s] = t5[ri][s];
    __syncthreads();

    if (t < 64) {
        ull* p = dmp + t * 80;
        const size_t base = (size_t)(r0 + t) * 20 + (size_t)ch * 5;
#pragma unroll
        for (int s = 0; s < 5; ++s) {
            ull best = ~0ull; int bp = 0;
            for (int q = 0; q < 80; ++q) {
                ull v = p[q];
                if (v < best) { best = v; bp = q; }
            }
            p[bp] = ~0ull;
            part[base + s] = best;
        }
    }
}

// ---------------- Kernel 3: per-row finalize ----------------
__global__ void finalize_kernel(const float* __restrict__ X,
                                const float* __restrict__ ns_g,
                                const ull* __restrict__ part,
                                float* __restrict__ out) {
    const int row = blockIdx.x;
    const int t   = threadIdx.x;  // 64 threads
    __shared__ ull keys[20];
    __shared__ __align__(16) float xr[64];
    __shared__ int excl[5];
    __shared__ float negterm[20];
    __shared__ float pos_s;

    if (t < 20) keys[t] = part[(size_t)row * 20 + t];
    if (t < 16) ((float4*)xr)[t] = ((const float4*)X)[(size_t)row * 16 + t];
    __syncthreads();

    if (t == 0) {
        ull b[5];
#pragma unroll
        for (int s = 0; s < 5; ++s) {
            ull best = ~0ull; int bp = 0;
            for (int q = 0; q < 20; ++q)
                if (keys[q] < best) { best = keys[q]; bp = q; }
            keys[bp] = ~0ull;
            b[s] = best;
        }
        // pos logsumexp over the 5 smallest distances
        float term[5], m = -INFINITY;
#pragma unroll
        for (int s = 0; s < 5; ++s) {
            float z = __uint_as_float((unsigned)(b[s] >> 32));
            term[s] = -acoshf(z) * TAU_INV;
            m = fmaxf(m, term[s]);
        }
        float sum = 0.f;
#pragma unroll
        for (int s = 0; s < 5; ++s) sum += expf(term[s] - m);
        pos_s = m + logf(sum);
        // sorted (ascending) excluded indices for the pool mapping
        int ids[5];
#pragma unroll
        for (int s = 0; s < 5; ++s) ids[s] = (int)(unsigned)(b[s] & 0xFFFFFFFFull);
        for (int i = 0; i < 4; ++i)
            for (int j = 0; j < 4 - i; ++j)
                if (ids[j] > ids[j + 1]) { int tmp = ids[j]; ids[j] = ids[j + 1]; ids[j + 1] = tmp; }
#pragma unroll
        for (int s = 0; s < 5; ++s) excl[s] = ids[s];
    }
    __syncthreads();

    if (t < 20) {
        unsigned m0 = (unsigned)(row * 20 + t);
        unsigned hi, lo;
        threefry2x32(0u, 42u, m0, m0 + TOTAL_SAMP, hi, lo);
        unsigned samp = ((hi % SPAN) * MULT + (lo % SPAN)) % SPAN;
        int col = (int)samp;
#pragma unroll
        for (int s = 0; s < 5; ++s) col += (excl[s] <= col) ? 1 : 0;

        float term;
        if (col == row) {
            term = -INFINITY;  // diagonal: dist = inf -> exp term 0
        } else {
            const float4* xc = (const float4*)(X + (size_t)col * D_K);
            float dot = 0.f;
#pragma unroll
            for (int k = 0; k < 16; ++k) {
                float4 a = ((float4*)xr)[k];
                float4 c = xc[k];
                dot = fmaf(a.x, c.x, dot);
                dot = fmaf(a.y, c.y, dot);
                dot = fmaf(a.z, c.z, dot);
                dot = fmaf(a.w, c.w, dot);
            }
            float nsi = ns_g[row], nsj = ns_g[col];
            float d2  = fmaxf(nsi + nsj - 2.f * dot, 0.f);
            float ci  = 1.f - fminf(nsi, 1.f);
            float cj  = 1.f - fminf(nsj, 1.f);
            float den = fmaxf(ci * cj, 1e-9f);
            float z   = fmaxf(1.f + 2.f * d2 / den, 1.f);
            term = -acoshf(z) * TAU_INV;
        }
        negterm[t] = term;
    }
    __syncthreads();

    if (t == 0) {
        float m = -INFINITY;
        for (int q = 0; q < 20; ++q) m = fmaxf(m, negterm[q]);
        float sum = 0.f;
        for (int q = 0; q < 20; ++q) sum += expf(negterm[q] - m);
        float neg = m + logf(sum);
        float loss = neg - pos_s;  // = -(pos_term - neg_term)
        atomicAdd(out, loss * (1.0f / 8192.0f));
    }
}

// ---------------- launch ----------------
extern "C" void kernel_launch(void* const* d_in, const int* in_sizes, int n_in,
                              void* d_out, int out_size, void* d_ws, size_t ws_size,
                              hipStream_t stream) {
    (void)in_sizes; (void)n_in; (void)out_size; (void)ws_size;
    const float* X = (const float*)d_in[0];
    float* out = (float*)d_out;

    float* ns_g = (float*)d_ws;                       // 8192 floats
    float* iv_g = ns_g + N_ROWS;                      // 8192 floats
    ull*   part = (ull*)((char*)d_ws + 65536);        // 8192*20 u64 = 1.25 MB

    hipMemsetAsync(out, 0, sizeof(float), stream);
    norms_kernel<<<N_ROWS / 256, 256, 0, stream>>>(X, ns_g, iv_g);
    topk_gram_kernel<<<512, 256, 0, stream>>>(X, ns_g, iv_g, part);
    finalize_kernel<<<N_ROWS, 64, 0, stream>>>(X, ns_g, part, out);
}

// Round 2
// 308.572 us; speedup vs baseline: 1.2215x; 1.2215x over previous
//
#include <hip/hip_runtime.h>
#include <cstdint>
#include <cstddef>

typedef unsigned long long ull;
typedef _Float16 f16x8 __attribute__((ext_vector_type(8)));
typedef float f32x4 __attribute__((ext_vector_type(4)));

#define N_ROWS 8192
#define SPAN   8187u   // n - k
#define MULT   1600u   // (2^32) % 8187
#define TAU_INV 10.0f
#define TOTAL_SAMP 163840u
#define INIT_KEY 0x7F800000FFFFFFFFull   // z=+inf, col=~0

// ---------------- threefry2x32 (JAX-compatible) ----------------
__device__ __forceinline__ void tf_round(unsigned &x0, unsigned &x1, int r) {
    x0 += x1; x1 = (x1 << r) | (x1 >> (32 - r)); x1 ^= x0;
}
__device__ __forceinline__ void threefry2x32(unsigned k0, unsigned k1,
                                             unsigned c0, unsigned c1,
                                             unsigned &o0, unsigned &o1) {
    unsigned ks2 = k0 ^ k1 ^ 0x1BD11BDAu;
    unsigned x0 = c0 + k0, x1 = c1 + k1;
    tf_round(x0, x1, 13); tf_round(x0, x1, 15); tf_round(x0, x1, 26); tf_round(x0, x1, 6);
    x0 += k1;  x1 += ks2 + 1u;
    tf_round(x0, x1, 17); tf_round(x0, x1, 29); tf_round(x0, x1, 16); tf_round(x0, x1, 24);
    x0 += ks2; x1 += k0 + 2u;
    tf_round(x0, x1, 13); tf_round(x0, x1, 15); tf_round(x0, x1, 26); tf_round(x0, x1, 6);
    x0 += k0;  x1 += k1 + 3u;
    tf_round(x0, x1, 17); tf_round(x0, x1, 29); tf_round(x0, x1, 16); tf_round(x0, x1, 24);
    x0 += k1;  x1 += ks2 + 4u;
    tf_round(x0, x1, 13); tf_round(x0, x1, 15); tf_round(x0, x1, 26); tf_round(x0, x1, 6);
    x0 += ks2; x1 += k0 + 5u;
    o0 = x0; o1 = x1;
}

// ---------------- async global->LDS (16B, wave-uniform LDS base) ----------------
__device__ __forceinline__ void async16(void* lds, const void* g) {
    __builtin_amdgcn_global_load_lds((const __attribute__((address_space(1))) void*)g,
                                     (__attribute__((address_space(3))) void*)lds, 16, 0, 0);
}

// Stage 1KB chunk q (0..7) of a 64x64-f16 tile (row-major, 128 B/row) with
// XOR-swizzled SOURCE chunk so the LDS dest stays linear (HW requirement).
// LDS slot (r, c) holds global chunk c ^ (r&7) of row r.
__device__ __forceinline__ void stage_chunk(char* lds_tile, const char* gtile, int q, int lane) {
    int off16 = (q << 6) + lane;      // 16B-unit index 0..511
    int r = off16 >> 3;
    int slot = off16 & 7;
    int csrc = slot ^ (r & 7);
    async16(lds_tile + (q << 10), gtile + r * 128 + (csrc << 4));
}

// Fragment read: 8 contiguous f16 of row `row`, 16B-chunk c (0..7), undoing swizzle.
__device__ __forceinline__ f16x8 read_frag(const char* tile, int row, int c) {
    return *(const f16x8*)(tile + row * 128 + (((c ^ (row & 7)) << 4)));
}

__device__ __forceinline__ void insert5(ull* a, ull kk) {
    bool l3 = kk < a[3], l2 = kk < a[2], l1 = kk < a[1], l0 = kk < a[0];
    a[4] = l3 ? a[3] : kk;
    a[3] = l3 ? (l2 ? a[2] : kk) : a[3];
    a[2] = l2 ? (l1 ? a[1] : kk) : a[2];
    a[1] = l1 ? (l0 ? a[0] : kk) : a[1];
    a[0] = l0 ? kk : a[0];
}

// ---------------- Kernel 1: norms + f16 hi/lo split ----------------
// 8 threads per row; thread handles 8 elements (32B in, 16B+16B out). Coalesced.
__global__ void prep_kernel(const float* __restrict__ X,
                            float2* __restrict__ nsiv,
                            char* __restrict__ Xhi,
                            char* __restrict__ Xlo) {
    int t = blockIdx.x * 256 + threadIdx.x;     // 0..65535
    int row = t >> 3, c = t & 7;
    const float4* src = (const float4*)(X + (size_t)row * 64 + c * 8);
    float4 a = src[0], b = src[1];
    float v[8] = {a.x, a.y, a.z, a.w, b.x, b.y, b.z, b.w};
    float ss = 0.f;
#pragma unroll
    for (int j = 0; j < 8; ++j) ss = fmaf(v[j], v[j], ss);
    ss += __shfl_xor(ss, 1);
    ss += __shfl_xor(ss, 2);
    ss += __shfl_xor(ss, 4);
    f16x8 h, l;
#pragma unroll
    for (int j = 0; j < 8; ++j) {
        _Float16 hh = (_Float16)v[j];
        h[j] = hh;
        l[j] = (_Float16)(v[j] - (float)hh);
    }
    *(f16x8*)(Xhi + (size_t)row * 128 + c * 16) = h;
    *(f16x8*)(Xlo + (size_t)row * 128 + c * 16) = l;
    if (c == 0) nsiv[row] = make_float2(ss, 1.0f / (1.0f - fminf(ss, 1.0f)));
}

// ---------------- Kernel 2: MFMA f16-split gram + fused top-5 ----------------
// grid 512 = 128 row-tiles x 4 col-chunks (2048 cols each). Block 256 = 4 waves.
// Wave w owns output rows r0 + 16w .. +15.
__global__ __launch_bounds__(256) void gram_topk(
        const char* __restrict__ Xhi, const char* __restrict__ Xlo,
        const float2* __restrict__ nsiv, ull* __restrict__ part) {
    __shared__ __align__(16) char lds[40960];
    char* Ahi = lds;
    char* Alo = lds + 8192;
    char* Bhi = lds + 16384;
    char* Blo = lds + 24576;
    ull* dmp = (ull*)lds;    // union; used only after the main loop

    const int t = threadIdx.x, lane = t & 63, wv = t >> 6;
    const int lx = lane & 15, lq = lane >> 4;
    const int r0 = (blockIdx.x >> 2) * 64;
    const int ch = blockIdx.x & 3;
    const int j0base = ch * 2048;

    // stage A tile (block-constant) and B tile for it=0
    const char* gAhi = Xhi + (size_t)r0 * 128;
    const char* gAlo = Xlo + (size_t)r0 * 128;
    stage_chunk(Ahi, gAhi, 2 * wv, lane);
    stage_chunk(Ahi, gAhi, 2 * wv + 1, lane);
    stage_chunk(Alo, gAlo, 2 * wv, lane);
    stage_chunk(Alo, gAlo, 2 * wv + 1, lane);
    stage_chunk(Bhi, Xhi + (size_t)j0base * 128, 2 * wv, lane);
    stage_chunk(Bhi, Xhi + (size_t)j0base * 128, 2 * wv + 1, lane);
    stage_chunk(Blo, Xlo + (size_t)j0base * 128, 2 * wv, lane);
    stage_chunk(Blo, Xlo + (size_t)j0base * 128, 2 * wv + 1, lane);

    // per-lane row stats (C/D layout: row = lq*4 + reg within the wave's strip)
    int grow[4]; float rns[4], riv[4];
#pragma unroll
    for (int r = 0; r < 4; ++r) {
        grow[r] = r0 + wv * 16 + lq * 4 + r;
        float2 nv = nsiv[grow[r]];
        rns[r] = nv.x; riv[r] = nv.y;
    }

    ull t5[4][5];
    float thr[4];
#pragma unroll
    for (int r = 0; r < 4; ++r) {
        thr[r] = __builtin_inff();
#pragma unroll
        for (int s = 0; s < 5; ++s) t5[r][s] = INIT_KEY;
    }

    __syncthreads();   // A and B(0) staged

    // A fragments: block-constant, hoisted out of the loop (A-frag m = lane&15)
    f16x8 ahi[2], alo[2];
#pragma unroll
    for (int kc = 0; kc < 2; ++kc) {
        ahi[kc] = read_frag(Ahi, wv * 16 + lx, kc * 4 + lq);
        alo[kc] = read_frag(Alo, wv * 16 + lx, kc * 4 + lq);
    }

    for (int it = 0; it < 32; ++it) {
        const int j0 = j0base + it * 64;

        // prefetch col stats for this tile (global, L2-hot; hidden under MFMA)
        float2 cn[4];
#pragma unroll
        for (int ct = 0; ct < 4; ++ct) cn[ct] = nsiv[j0 + ct * 16 + lx];

        f32x4 acc[4];
#pragma unroll
        for (int ct = 0; ct < 4; ++ct) {
            f16x8 bh0 = read_frag(Bhi, ct * 16 + lx, lq);
            f16x8 bh1 = read_frag(Bhi, ct * 16 + lx, 4 + lq);
            f16x8 bl0 = read_frag(Blo, ct * 16 + lx, lq);
            f16x8 bl1 = read_frag(Blo, ct * 16 + lx, 4 + lq);
            f32x4 a = {0.f, 0.f, 0.f, 0.f};
            a = __builtin_amdgcn_mfma_f32_16x16x32_f16(ahi[0], bh0, a, 0, 0, 0);
            a = __builtin_amdgcn_mfma_f32_16x16x32_f16(ahi[1], bh1, a, 0, 0, 0);
            a = __builtin_amdgcn_mfma_f32_16x16x32_f16(ahi[0], bl0, a, 0, 0, 0);
            a = __builtin_amdgcn_mfma_f32_16x16x32_f16(ahi[1], bl1, a, 0, 0, 0);
            a = __builtin_amdgcn_mfma_f32_16x16x32_f16(alo[0], bh0, a, 0, 0, 0);
            a = __builtin_amdgcn_mfma_f32_16x16x32_f16(alo[1], bh1, a, 0, 0, 0);
            acc[ct] = a;
        }

        __syncthreads();   // all waves done reading B(it)

        if (it + 1 < 32) {   // async-stage next B tile; flies during selection
            const char* gBh = Xhi + (size_t)(j0 + 64) * 128;
            const char* gBl = Xlo + (size_t)(j0 + 64) * 128;
            stage_chunk(Bhi, gBh, 2 * wv, lane);
            stage_chunk(Bhi, gBh, 2 * wv + 1, lane);
            stage_chunk(Blo, gBl, 2 * wv, lane);
            stage_chunk(Blo, gBl, 2 * wv + 1, lane);
        }

        // selection: z = 1 + 2*d2*iv_i*iv_j, float-threshold early-out
        float cns[4], civ2[4];
#pragma unroll
        for (int ct = 0; ct < 4; ++ct) { cns[ct] = cn[ct].x; civ2[ct] = 2.0f * cn[ct].y; }

#pragma unroll
        for (int ct = 0; ct < 4; ++ct) {
#pragma unroll
            for (int r = 0; r < 4; ++r) {
                float g  = acc[ct][r];
                float d2 = fmaf(-2.0f, g, rns[r] + cns[ct]);
                float z  = fmaf(d2 * riv[r], civ2[ct], 1.0f);
                if (z < thr[r]) {
                    int gcol = j0 + ct * 16 + lx;
                    if (gcol != grow[r]) {
                        ull kk = ((ull)__float_as_uint(z) << 32) | (unsigned)gcol;
                        if (kk < t5[r][4]) {
                            insert5(t5[r], kk);
                            thr[r] = __uint_as_float((unsigned)(t5[r][4] >> 32));
                        }
                    }
                }
            }
        }

        __syncthreads();   // B(it+1) staged (vmcnt drained by barrier)
    }

    // dump per-lane top5 and merge to per-row chunk top5
#pragma unroll
    for (int r = 0; r < 4; ++r)
#pragma unroll
        for (int s = 0; s < 5; ++s)
            dmp[(size_t)(wv * 16 + lq * 4 + r) * 80 + lx * 5 + s] = t5[r][s];
    __syncthreads();

    if (t < 64) {
        ull* p = dmp + (size_t)t * 80;
        const size_t base = (size_t)(r0 + t) * 20 + (size_t)ch * 5;
#pragma unroll
        for (int s = 0; s < 5; ++s) {
            ull best = ~0ull; int bp = 0;
            for (int q = 0; q < 80; ++q) {
                ull v = p[q];
                if (v < best) { best = v; bp = q; }
            }
            p[bp] = ~0ull;
            part[base + s] = best;
        }
    }
}

// ---------------- Kernel 3: per-row finalize ----------------
__global__ void finalize_kernel(const float* __restrict__ X,
                                const float2* __restrict__ nsiv,
                                const ull* __restrict__ part,
                                float* __restrict__ out) {
    const int row = blockIdx.x;
    const int t   = threadIdx.x;  // 64 threads
    __shared__ ull keys[20];
    __shared__ __align__(16) float xr[64];
    __shared__ int excl[5];
    __shared__ float negterm[20];
    __shared__ float pos_s;

    if (t < 20) keys[t] = part[(size_t)row * 20 + t];
    if (t < 16) ((float4*)xr)[t] = ((const float4*)X)[(size_t)row * 16 + t];
    __syncthreads();

    if (t == 0) {
        ull b[5];
#pragma unroll
        for (int s = 0; s < 5; ++s) {
            ull best = ~0ull; int bp = 0;
            for (int q = 0; q < 20; ++q)
                if (keys[q] < best) { best = keys[q]; bp = q; }
            keys[bp] = ~0ull;
            b[s] = best;
        }
        float term[5], m = -INFINITY;
#pragma unroll
        for (int s = 0; s < 5; ++s) {
            float z = __uint_as_float((unsigned)(b[s] >> 32));
            z = fmaxf(z, 1.0f);
            term[s] = -acoshf(z) * TAU_INV;
            m = fmaxf(m, term[s]);
        }
        float sum = 0.f;
#pragma unroll
        for (int s = 0; s < 5; ++s) sum += expf(term[s] - m);
        pos_s = m + logf(sum);
        int ids[5];
#pragma unroll
        for (int s = 0; s < 5; ++s) ids[s] = (int)(unsigned)(b[s] & 0xFFFFFFFFull);
        for (int i = 0; i < 4; ++i)
            for (int j = 0; j < 4 - i; ++j)
                if (ids[j] > ids[j + 1]) { int tmp = ids[j]; ids[j] = ids[j + 1]; ids[j + 1] = tmp; }
#pragma unroll
        for (int s = 0; s < 5; ++s) excl[s] = ids[s];
    }
    __syncthreads();

    if (t < 20) {
        unsigned m0 = (unsigned)(row * 20 + t);
        unsigned hi, lo;
        threefry2x32(0u, 42u, m0, m0 + TOTAL_SAMP, hi, lo);
        unsigned samp = ((hi % SPAN) * MULT + (lo % SPAN)) % SPAN;
        int col = (int)samp;
#pragma unroll
        for (int s = 0; s < 5; ++s) col += (excl[s] <= col) ? 1 : 0;

        float term;
        if (col == row) {
            term = -INFINITY;
        } else {
            const float4* xc = (const float4*)(X + (size_t)col * 64);
            float dot = 0.f;
#pragma unroll
            for (int k = 0; k < 16; ++k) {
                float4 a = ((float4*)xr)[k];
                float4 c = xc[k];
                dot = fmaf(a.x, c.x, dot);
                dot = fmaf(a.y, c.y, dot);
                dot = fmaf(a.z, c.z, dot);
                dot = fmaf(a.w, c.w, dot);
            }
            float nsi = nsiv[row].x, nsj = nsiv[col].x;
            float d2  = fmaxf(nsi + nsj - 2.f * dot, 0.f);
            float ci  = 1.f - fminf(nsi, 1.f);
            float cj  = 1.f - fminf(nsj, 1.f);
            float den = fmaxf(ci * cj, 1e-9f);
            float z   = fmaxf(1.f + 2.f * d2 / den, 1.f);
            term = -acoshf(z) * TAU_INV;
        }
        negterm[t] = term;
    }
    __syncthreads();

    if (t == 0) {
        float m = -INFINITY;
        for (int q = 0; q < 20; ++q) m = fmaxf(m, negterm[q]);
        float sum = 0.f;
        for (int q = 0; q < 20; ++q) sum += expf(negterm[q] - m);
        float neg = m + logf(sum);
        float loss = neg - pos_s;
        atomicAdd(out, loss * (1.0f / 8192.0f));
    }
}

// ---------------- launch ----------------
extern "C" void kernel_launch(void* const* d_in, const int* in_sizes, int n_in,
                              void* d_out, int out_size, void* d_ws, size_t ws_size,
                              hipStream_t stream) {
    (void)in_sizes; (void)n_in; (void)out_size; (void)ws_size;
    const float* X = (const float*)d_in[0];
    float* out = (float*)d_out;

    // workspace layout (bytes):
    float2* nsiv = (float2*)d_ws;                            // 65536
    char*   Xhi  = (char*)d_ws + 65536;                      // 1 MB
    char*   Xlo  = (char*)d_ws + 65536 + 1048576;            // 1 MB
    ull*    part = (ull*)((char*)d_ws + 65536 + 2097152);    // 1.25 MB

    hipMemsetAsync(out, 0, sizeof(float), stream);
    prep_kernel<<<256, 256, 0, stream>>>(X, nsiv, Xhi, Xlo);
    gram_topk<<<512, 256, 0, stream>>>(Xhi, Xlo, nsiv, part);
    finalize_kernel<<<N_ROWS, 64, 0, stream>>>(X, nsiv, part, out);
}

// Round 4
// 210.251 us; speedup vs baseline: 1.7927x; 1.4676x over previous
//
#include <hip/hip_runtime.h>
#include <cstdint>
#include <cstddef>

typedef unsigned long long ull;
typedef _Float16 f16x8 __attribute__((ext_vector_type(8)));
typedef float f32x4 __attribute__((ext_vector_type(4)));

#define N_ROWS 8192
#define SPAN   8187u   // n - k
#define MULT   1600u   // (2^32) % 8187
#define TAU_INV 10.0f
#define TOTAL_SAMP 163840u
#define INIT_KEY 0x7F800000FFFFFFFFull   // q=+inf, col=~0

// ---------------- threefry2x32 (JAX-compatible) ----------------
__device__ __forceinline__ void tf_round(unsigned &x0, unsigned &x1, int r) {
    x0 += x1; x1 = (x1 << r) | (x1 >> (32 - r)); x1 ^= x0;
}
__device__ __forceinline__ void threefry2x32(unsigned k0, unsigned k1,
                                             unsigned c0, unsigned c1,
                                             unsigned &o0, unsigned &o1) {
    unsigned ks2 = k0 ^ k1 ^ 0x1BD11BDAu;
    unsigned x0 = c0 + k0, x1 = c1 + k1;
    tf_round(x0, x1, 13); tf_round(x0, x1, 15); tf_round(x0, x1, 26); tf_round(x0, x1, 6);
    x0 += k1;  x1 += ks2 + 1u;
    tf_round(x0, x1, 17); tf_round(x0, x1, 29); tf_round(x0, x1, 16); tf_round(x0, x1, 24);
    x0 += ks2; x1 += k0 + 2u;
    tf_round(x0, x1, 13); tf_round(x0, x1, 15); tf_round(x0, x1, 26); tf_round(x0, x1, 6);
    x0 += k0;  x1 += k1 + 3u;
    tf_round(x0, x1, 17); tf_round(x0, x1, 29); tf_round(x0, x1, 16); tf_round(x0, x1, 24);
    x0 += k1;  x1 += ks2 + 4u;
    tf_round(x0, x1, 13); tf_round(x0, x1, 15); tf_round(x0, x1, 26); tf_round(x0, x1, 6);
    x0 += ks2; x1 += k0 + 5u;
    o0 = x0; o1 = x1;
}

// ---------------- async global->LDS (16B) ----------------
__device__ __forceinline__ void async16(void* lds, const void* g) {
    __builtin_amdgcn_global_load_lds((const __attribute__((address_space(1))) void*)g,
                                     (__attribute__((address_space(3))) void*)lds, 16, 0, 0);
}

// Stage 1KB chunk q (0..7) of a 64x64-f16 tile (row-major, 128 B/row), XOR-swizzled
// source chunk so LDS dest stays lane-linear. LDS slot (r,c) = global chunk c^(r&7).
__device__ __forceinline__ void stage_chunk(char* lds_tile, const char* gtile, int q, int lane) {
    int off16 = (q << 6) + lane;
    int r = off16 >> 3;
    int slot = off16 & 7;
    int csrc = slot ^ (r & 7);
    async16(lds_tile + (q << 10), gtile + r * 128 + (csrc << 4));
}

__device__ __forceinline__ f16x8 read_frag(const char* tile, int row, int c) {
    return *(const f16x8*)(tile + row * 128 + (((c ^ (row & 7)) << 4)));
}

__device__ __forceinline__ void insert5(ull* a, ull kk) {
    bool l3 = kk < a[3], l2 = kk < a[2], l1 = kk < a[1], l0 = kk < a[0];
    a[4] = l3 ? a[3] : kk;
    a[3] = l3 ? (l2 ? a[2] : kk) : a[3];
    a[2] = l2 ? (l1 ? a[1] : kk) : a[2];
    a[1] = l1 ? (l0 ? a[0] : kk) : a[1];
    a[0] = l0 ? kk : a[0];
}

__device__ __forceinline__ float wave_maxf(float v) {
#pragma unroll
    for (int o = 32; o; o >>= 1) v = fmaxf(v, __shfl_xor(v, o));
    return v;
}
__device__ __forceinline__ float wave_sumf(float v) {
#pragma unroll
    for (int o = 32; o; o >>= 1) v += __shfl_xor(v, o);
    return v;
}
__device__ __forceinline__ ull wave_minu64(ull v) {
#pragma unroll
    for (int o = 32; o; o >>= 1) {
        ull w = __shfl_xor(v, o);
        v = (w < v) ? w : v;
    }
    return v;
}

// ---------------- Kernel 1: norms + f16 hi/lo split ----------------
__global__ void prep_kernel(const float* __restrict__ X,
                            float2* __restrict__ nsiv,
                            char* __restrict__ Xhi,
                            char* __restrict__ Xlo) {
    int t = blockIdx.x * 256 + threadIdx.x;
    int row = t >> 3, c = t & 7;
    const float4* src = (const float4*)(X + (size_t)row * 64 + c * 8);
    float4 a = src[0], b = src[1];
    float v[8] = {a.x, a.y, a.z, a.w, b.x, b.y, b.z, b.w};
    float ss = 0.f;
#pragma unroll
    for (int j = 0; j < 8; ++j) ss = fmaf(v[j], v[j], ss);
    ss += __shfl_xor(ss, 1);
    ss += __shfl_xor(ss, 2);
    ss += __shfl_xor(ss, 4);
    f16x8 h, l;
#pragma unroll
    for (int j = 0; j < 8; ++j) {
        _Float16 hh = (_Float16)v[j];
        h[j] = hh;
        l[j] = (_Float16)(v[j] - (float)hh);
    }
    *(f16x8*)(Xhi + (size_t)row * 128 + c * 16) = h;
    *(f16x8*)(Xlo + (size_t)row * 128 + c * 16) = l;
    if (c == 0) nsiv[row] = make_float2(ss, 1.0f / (1.0f - fminf(ss, 1.0f)));
}

// ---------------- Kernel 2: MFMA gram + fused top-5, single-barrier dbuf ----------------
// grid 512 = 128 row-tiles x 4 col-chunks (2048 cols). 4 waves; wave w owns rows r0+16w..+15.
__global__ __launch_bounds__(256, 3) void gram_topk(
        const char* __restrict__ Xhi, const char* __restrict__ Xlo,
        const float2* __restrict__ nsiv, ull* __restrict__ part) {
    __shared__ __align__(16) char lds[49152];
    char* Ahi = lds;
    char* Alo = lds + 8192;
    ull* dmp = (ull*)lds;                         // union, post-loop only

    const int t = threadIdx.x, lane = t & 63, wv = t >> 6;
    const int lx = lane & 15, lq = lane >> 4;
    const int r0 = (blockIdx.x >> 2) * 64;
    const int ch = blockIdx.x & 3;
    const int j0base = ch * 2048;

    // stage A (block-constant) and B buf0 (tile 0)
    const char* gAhi = Xhi + (size_t)r0 * 128;
    const char* gAlo = Xlo + (size_t)r0 * 128;
    stage_chunk(Ahi, gAhi, 2 * wv, lane);
    stage_chunk(Ahi, gAhi, 2 * wv + 1, lane);
    stage_chunk(Alo, gAlo, 2 * wv, lane);
    stage_chunk(Alo, gAlo, 2 * wv + 1, lane);
    {
        char* b0 = lds + 16384;
        stage_chunk(b0,        Xhi + (size_t)j0base * 128, 2 * wv, lane);
        stage_chunk(b0,        Xhi + (size_t)j0base * 128, 2 * wv + 1, lane);
        stage_chunk(b0 + 8192, Xlo + (size_t)j0base * 128, 2 * wv, lane);
        stage_chunk(b0 + 8192, Xlo + (size_t)j0base * 128, 2 * wv + 1, lane);
    }

    // per-lane row stats (C/D layout: row = lq*4 + reg)
    int grow[4]; float rns[4];
#pragma unroll
    for (int r = 0; r < 4; ++r) {
        grow[r] = r0 + wv * 16 + lq * 4 + r;
        rns[r] = nsiv[grow[r]].x;
    }

    ull t5[4][5];
    float thr[4];
#pragma unroll
    for (int r = 0; r < 4; ++r) {
        thr[r] = __builtin_inff();
#pragma unroll
        for (int s = 0; s < 5; ++s) t5[r][s] = INIT_KEY;
    }

    __syncthreads();   // A + B0 staged

    f16x8 ahi[2], alo[2];
#pragma unroll
    for (int kc = 0; kc < 2; ++kc) {
        ahi[kc] = read_frag(Ahi, wv * 16 + lx, kc * 4 + lq);
        alo[kc] = read_frag(Alo, wv * 16 + lx, kc * 4 + lq);
    }

    for (int it = 0; it < 32; ++it) {
        const int j0 = j0base + it * 64;
        char* cur = lds + ((it & 1) ? 32768 : 16384);

        if (it + 1 < 32) {   // stage next tile into the other buffer; flies all iteration
            char* nxt = lds + ((it & 1) ? 16384 : 32768);
            const char* gBh = Xhi + (size_t)(j0 + 64) * 128;
            const char* gBl = Xlo + (size_t)(j0 + 64) * 128;
            stage_chunk(nxt,        gBh, 2 * wv, lane);
            stage_chunk(nxt,        gBh, 2 * wv + 1, lane);
            stage_chunk(nxt + 8192, gBl, 2 * wv, lane);
            stage_chunk(nxt + 8192, gBl, 2 * wv + 1, lane);
        }

        float2 cn[4];
#pragma unroll
        for (int ct = 0; ct < 4; ++ct) cn[ct] = nsiv[j0 + ct * 16 + lx];

        f32x4 acc[4];
#pragma unroll
        for (int ct = 0; ct < 4; ++ct) {
            f16x8 bh0 = read_frag(cur, ct * 16 + lx, lq);
            f16x8 bh1 = read_frag(cur, ct * 16 + lx, 4 + lq);
            f16x8 bl0 = read_frag(cur + 8192, ct * 16 + lx, lq);
            f16x8 bl1 = read_frag(cur + 8192, ct * 16 + lx, 4 + lq);
            f32x4 a = {0.f, 0.f, 0.f, 0.f};
            a = __builtin_amdgcn_mfma_f32_16x16x32_f16(ahi[0], bh0, a, 0, 0, 0);
            a = __builtin_amdgcn_mfma_f32_16x16x32_f16(ahi[1], bh1, a, 0, 0, 0);
            a = __builtin_amdgcn_mfma_f32_16x16x32_f16(ahi[0], bl0, a, 0, 0, 0);
            a = __builtin_amdgcn_mfma_f32_16x16x32_f16(ahi[1], bl1, a, 0, 0, 0);
            a = __builtin_amdgcn_mfma_f32_16x16x32_f16(alo[0], bh0, a, 0, 0, 0);
            a = __builtin_amdgcn_mfma_f32_16x16x32_f16(alo[1], bh1, a, 0, 0, 0);
            acc[ct] = a;
        }

        // selection with monotone proxy q = d2 * civ_j  (per-row iv_i dropped)
#pragma unroll
        for (int ct = 0; ct < 4; ++ct) {
            const float civ    = cn[ct].y;
            const float cnsciv = cn[ct].x * civ;
            const float m2civ  = -2.0f * civ;
            const int   gcol   = j0 + ct * 16 + lx;
#pragma unroll
            for (int r = 0; r < 4; ++r) {
                float base = fmaf(rns[r], civ, cnsciv);
                float q    = fmaf(acc[ct][r], m2civ, base);
                if (q < thr[r]) {
                    if (gcol != grow[r]) {
                        ull kk = ((ull)__float_as_uint(q) << 32) | (unsigned)gcol;
                        if (kk < t5[r][4]) {
                            insert5(t5[r], kk);
                            thr[r] = __uint_as_float((unsigned)(t5[r][4] >> 32));
                        }
                    }
                }
            }
        }

        __syncthreads();   // all waves done with cur; next buffer fully staged
    }

    // dump per-lane top5 and merge to per-row chunk top5 (keys carry col; q is proxy)
#pragma unroll
    for (int r = 0; r < 4; ++r)
#pragma unroll
        for (int s = 0; s < 5; ++s)
            dmp[(size_t)(wv * 16 + lq * 4 + r) * 80 + lx * 5 + s] = t5[r][s];
    __syncthreads();

    if (t < 64) {
        ull* p = dmp + (size_t)t * 80;
        const size_t base = (size_t)(r0 + t) * 20 + (size_t)ch * 5;
#pragma unroll
        for (int s = 0; s < 5; ++s) {
            ull best = ~0ull; int bp = 0;
            for (int q = 0; q < 80; ++q) {
                ull v = p[q];
                if (v < best) { best = v; bp = q; }
            }
            p[bp] = ~0ull;
            part[base + s] = best;
        }
    }
}

// ---------------- Kernel 3: finalize, 4 rows/block (wave per row), shuffle-parallel ----------------
__global__ __launch_bounds__(256) void finalize_kernel(
        const float* __restrict__ X, const float2* __restrict__ nsiv,
        const ull* __restrict__ part, float* __restrict__ rowloss) {
    const int t = threadIdx.x, lane = t & 63, wv = t >> 6;
    const int row = blockIdx.x * 4 + wv;

    // merge chunk top-5s (20 keys) -> global top-5 via 5 wave-min passes
    ull key = (lane < 20) ? part[(size_t)row * 20 + lane] : ~0ull;
    ull b[5];
#pragma unroll
    for (int s = 0; s < 5; ++s) {
        ull m = wave_minu64(key);
        b[s] = m;
        if (key == m) key = ~0ull;   // cols unique across chunks -> unique min
    }

    int pcol[5], ids[5];
#pragma unroll
    for (int s = 0; s < 5; ++s) { pcol[s] = (int)(unsigned)(b[s] & 0xFFFFFFFFull); ids[s] = pcol[s]; }
    // sort excluded ids ascending (tiny; every lane duplicates)
    for (int i = 0; i < 4; ++i)
        for (int j = 0; j < 4 - i; ++j)
            if (ids[j] > ids[j + 1]) { int tmp = ids[j]; ids[j] = ids[j + 1]; ids[j + 1] = tmp; }

    // column for this lane: lanes 0..19 = sampled negatives, 20..24 = positives
    int col = row;
    if (lane < 20) {
        unsigned m0 = (unsigned)(row * 20 + lane);
        unsigned hi, lo;
        threefry2x32(0u, 42u, m0, m0 + TOTAL_SAMP, hi, lo);
        unsigned samp = ((hi % SPAN) * MULT + (lo % SPAN)) % SPAN;
        int c = (int)samp;
#pragma unroll
        for (int s = 0; s < 5; ++s) c += (ids[s] <= c) ? 1 : 0;
        col = c;
    } else if (lane < 25) {
        col = pcol[lane - 20];
    }

    // exact fp32 Poincare distance term  -dist/tau  (diagonal -> -inf)
    float term = -INFINITY;
    if (lane < 25 && col != row) {
        const float4* xr = (const float4*)(X + (size_t)row * 64);
        const float4* xc = (const float4*)(X + (size_t)col * 64);
        float dot = 0.f;
#pragma unroll
        for (int k = 0; k < 16; ++k) {
            float4 a = xr[k];
            float4 c = xc[k];
            dot = fmaf(a.x, c.x, dot);
            dot = fmaf(a.y, c.y, dot);
            dot = fmaf(a.z, c.z, dot);
            dot = fmaf(a.w, c.w, dot);
        }
        float nsi = nsiv[row].x, nsj = nsiv[col].x;
        float d2  = fmaxf(nsi + nsj - 2.f * dot, 0.f);
        float ci  = 1.f - fminf(nsi, 1.f);
        float cj  = 1.f - fminf(nsj, 1.f);
        float den = fmaxf(ci * cj, 1e-9f);
        float z   = fmaxf(1.f + 2.f * d2 / den, 1.f);
        term = -acoshf(z) * TAU_INV;
    }

    // two masked LSEs across the wave
    float negt = (lane < 20) ? term : -INFINITY;
    float post = (lane >= 20 && lane < 25) ? term : -INFINITY;

    float nm = wave_maxf(negt);
    float ne = (lane < 20 && negt != -INFINITY) ? expf(negt - nm) : 0.f;
    float neg = nm + logf(wave_sumf(ne));

    float pm = wave_maxf(post);
    float pe = (lane >= 20 && lane < 25) ? expf(post - pm) : 0.f;
    float pos = pm + logf(wave_sumf(pe));

    if (lane == 0) rowloss[row] = neg - pos;
}

// ---------------- Kernel 4: deterministic tree sum ----------------
__global__ void reduce_kernel(const float* __restrict__ rl, float* __restrict__ out) {
    const int t = threadIdx.x;
    float s = 0.f;
#pragma unroll
    for (int i = 0; i < 32; ++i) s += rl[t + 256 * i];
#pragma unroll
    for (int o = 32; o; o >>= 1) s += __shfl_xor(s, o);
    __shared__ float ws4[4];
    if ((t & 63) == 0) ws4[t >> 6] = s;
    __syncthreads();
    if (t == 0) out[0] = (ws4[0] + ws4[1] + ws4[2] + ws4[3]) * (1.0f / 8192.0f);
}

// ---------------- launch ----------------
extern "C" void kernel_launch(void* const* d_in, const int* in_sizes, int n_in,
                              void* d_out, int out_size, void* d_ws, size_t ws_size,
                              hipStream_t stream) {
    (void)in_sizes; (void)n_in; (void)out_size; (void)ws_size;
    const float* X = (const float*)d_in[0];
    float* out = (float*)d_out;

    float2* nsiv    = (float2*)d_ws;                                  // 64 KB
    char*   Xhi     = (char*)d_ws + 65536;                            // 1 MB
    char*   Xlo     = (char*)d_ws + 65536 + 1048576;                  // 1 MB
    ull*    part    = (ull*)((char*)d_ws + 65536 + 2097152);          // 1.25 MB
    float*  rowloss = (float*)((char*)d_ws + 65536 + 2097152 + 1310720); // 32 KB

    prep_kernel<<<256, 256, 0, stream>>>(X, nsiv, Xhi, Xlo);
    gram_topk<<<512, 256, 0, stream>>>(Xhi, Xlo, nsiv, part);
    finalize_kernel<<<2048, 256, 0, stream>>>(X, nsiv, part, rowloss);
    reduce_kernel<<<1, 256, 0, stream>>>(rowloss, out);
}